// Round 8
// baseline (446.216 us; speedup 1.0000x reference)
//
#include <hip/hip_runtime.h>

#define T_ 1024
#define H_ 2048
#define I_ 3200
#define E_ 8

typedef float fvec4 __attribute__((ext_vector_type(4)));
typedef float f32x4 __attribute__((ext_vector_type(4)));
typedef __bf16 bf16x8 __attribute__((ext_vector_type(8)));
typedef unsigned short u16x4 __attribute__((ext_vector_type(4)));

typedef const __attribute__((address_space(1))) void* gp1_t;
typedef __attribute__((address_space(3))) void* sp3_t;

// ---- ws layout (bytes) ----
// 0   : cnt[8]
// 32  : wk1, wk2 (work-steal counters)
// 64  : base[16]
// 128 : nchunks, chunkE[16], chunkM[16]
#define WS_CHUNK 128
#define WS_TOK   512
#define WS_GATE  33280
#define WS_XB    66560
#define WS_ACT   4261888   // 3328 rows x 3200 bf16 (slack rows OOB-safe)
#define MAXCH    16

#define BARX() { asm volatile("s_waitcnt lgkmcnt(0)" ::: "memory"); \
    __builtin_amdgcn_sched_barrier(0); __builtin_amdgcn_s_barrier(); \
    __builtin_amdgcn_sched_barrier(0); }

// ---------------- router + sparsemixer + list build + x->bf16 ----------------
__global__ __launch_bounds__(256) void router_kernel(const float* __restrict__ x,
                                                     const float* __restrict__ gw,
                                                     int* __restrict__ cnt,
                                                     int* __restrict__ tok,
                                                     float* __restrict__ gate,
                                                     unsigned short* __restrict__ xb) {
  const int lane = threadIdx.x & 63;
  const int wv = threadIdx.x >> 6;
  const int t = blockIdx.x * 4 + wv;

  const float* xp = x + (size_t)t * H_;
  fvec4 xr[8];
#pragma unroll
  for (int j = 0; j < 8; ++j) xr[j] = *(const fvec4*)(xp + j * 256 + lane * 4);

  unsigned short* xbp = xb + (size_t)t * H_;
#pragma unroll
  for (int j = 0; j < 8; ++j) {
    u16x4 o;
#pragma unroll
    for (int c = 0; c < 4; ++c) o[c] = __builtin_bit_cast(unsigned short, (__bf16)xr[j][c]);
    *(u16x4*)(xbp + j * 256 + lane * 4) = o;
  }

  float s[E_];
#pragma unroll
  for (int e = 0; e < E_; ++e) {
    const float* gp = gw + (size_t)e * H_;
    float p = 0.f;
#pragma unroll
    for (int j = 0; j < 8; ++j) {
      fvec4 g = *(const fvec4*)(gp + j * 256 + lane * 4);
      p = fmaf(xr[j][0], g[0], p); p = fmaf(xr[j][1], g[1], p);
      p = fmaf(xr[j][2], g[2], p); p = fmaf(xr[j][3], g[3], p);
    }
#pragma unroll
    for (int off = 32; off > 0; off >>= 1) p += __shfl_xor(p, off);
    s[e] = p;
  }

  float max1 = s[0]; int i1 = 0;
#pragma unroll
  for (int e = 1; e < E_; ++e) if (s[e] > max1) { max1 = s[e]; i1 = e; }
  float den1 = 0.f;
#pragma unroll
  for (int e = 0; e < E_; ++e) {
    float factor = fmaxf(fabsf(s[e]), max1);
    if ((max1 - s[e]) <= 0.02f * factor) den1 += expf(s[e] - max1);
  }
  float mult1 = 1.f / den1;

  float max2 = -INFINITY; int i2 = 0;
#pragma unroll
  for (int e = 0; e < E_; ++e) if (e != i1 && s[e] > max2) { max2 = s[e]; i2 = e; }
  float den2 = 0.f;
#pragma unroll
  for (int e = 0; e < E_; ++e) {
    if (e == i1) continue;
    float factor = fmaxf(fabsf(s[e]), max2);
    if ((max2 - s[e]) <= 0.02f * factor) den2 += expf(s[e] - max2);
  }
  float mult2 = 1.f / den2;

  if (lane == 0) {
    int p1 = atomicAdd(&cnt[i1], 1); tok[i1 * T_ + p1] = t; gate[i1 * T_ + p1] = mult1;
    int p2 = atomicAdd(&cnt[i2], 1); tok[i2 * T_ + p2] = t; gate[i2 * T_ + p2] = mult2;
  }
}

// ---------------- prefix (128-pad) + chunk table (256-row chunks) ----------------
__global__ void prefix_kernel(const int* __restrict__ cnt, int* __restrict__ base,
                              int* __restrict__ chunk) {
  if (threadIdx.x == 0 && blockIdx.x == 0) {
    int a = 0, c = 0;
    for (int e = 0; e < E_; ++e) {
      base[e] = a;
      int pc = (cnt[e] + 127) & ~127;
      for (int m = 0; m < pc; m += 256) { chunk[1 + c] = e; chunk[1 + MAXCH + c] = m; ++c; }
      a += pc;
    }
    base[E_] = a;
    chunk[0] = c;
  }
}

// ---- FFN1: persistent, BM=256, BN=32, BK=64, 8 waves, 1 barrier/region ----
__global__ __launch_bounds__(512, 4) void ffn1_kernel(
    const unsigned short* __restrict__ xb, const float* __restrict__ w1,
    const float* __restrict__ w3, const int* __restrict__ cnt,
    const int* __restrict__ base, const int* __restrict__ chunk,
    const int* __restrict__ tokl, unsigned short* __restrict__ actb,
    int* __restrict__ wk) {
  const int tid = threadIdx.x;
  const int lane = tid & 63, wv = tid >> 6;   // 8 waves
  const int wm = wv >> 1, wn = wv & 1;        // per-wave 64x16 out

  __shared__ unsigned short Ab[2][256 * 64];  // 64 KiB
  __shared__ unsigned short B1s[2][32 * 64];  // 8 KiB
  __shared__ unsigned short B3s[2][32 * 64];  // 8 KiB   -> 80 KiB total
  __shared__ int sItem;

  const int nwork = chunk[0] * 100;           // 100 n-tiles of 32
  const int brow = tid >> 4, w = tid & 15;
  const int wbyte = brow * 128 + (((w >> 1) ^ (brow & 7)) << 4) + (w & 1) * 8;
  const int colg = ((lane & 7) ^ ((lane >> 3) & 7)) * 8;
  const int NT = H_ / 64;                     // 32

  for (;;) {
    __syncthreads();
    if (tid == 0) sItem = atomicAdd(wk, 1);
    __syncthreads();
    const int item = sItem;
    if (item >= nwork) return;
    const int c = item / 100;
    const int n0 = (item - c * 100) * 32;
    const int e = chunk[1 + c];
    const int m_base = chunk[1 + MAXCH + c];
    const int ab = base[e];
    const int count = cnt[e];

    const unsigned short* aSrc[4];
#pragma unroll
    for (int i = 0; i < 4; ++i) {
      int r = m_base + wv * 32 + i * 8 + (lane >> 3);
      if (r >= count) r = count - 1;
      aSrc[i] = xb + (size_t)tokl[e * T_ + r] * H_ + colg;
    }
    const float* b1p = w1 + ((size_t)e * I_ + n0 + brow) * H_ + w * 4;
    const float* b3p = w3 + ((size_t)e * I_ + n0 + brow) * H_ + w * 4;

    f32x4 acc1[4], acc3[4];
#pragma unroll
    for (int mi = 0; mi < 4; ++mi) { acc1[mi] = (f32x4){0,0,0,0}; acc3[mi] = (f32x4){0,0,0,0}; }

    auto STAGE_A = [&](unsigned short* dst, int kb) {
#pragma unroll
      for (int i = 0; i < 4; ++i)
        __builtin_amdgcn_global_load_lds((gp1_t)(aSrc[i] + kb),
                                         (sp3_t)(dst + (wv * 32 + i * 8) * 64), 16, 0, 0);
    };
    auto LOADB = [&](fvec4& r1, fvec4& r3, int kb) {
      r1 = *(const fvec4*)(b1p + kb);
      r3 = *(const fvec4*)(b3p + kb);
    };
    auto CVTW = [&](fvec4& r1, fvec4& r3, int buf) {
      u16x4 v, u;
#pragma unroll
      for (int cc = 0; cc < 4; ++cc) {
        v[cc] = __builtin_bit_cast(unsigned short, (__bf16)r1[cc]);
        u[cc] = __builtin_bit_cast(unsigned short, (__bf16)r3[cc]);
      }
      *(u16x4*)((char*)B1s[buf] + wbyte) = v;
      *(u16x4*)((char*)B3s[buf] + wbyte) = u;
    };
    auto STEP = [&](const unsigned short* A_, int bbuf) {
#pragma unroll
      for (int kk = 0; kk < 2; ++kk) {
        const int c16 = kk * 4 + (lane >> 4);
        bf16x8 af[4];
#pragma unroll
        for (int mi = 0; mi < 4; ++mi) {
          int ar = wm * 64 + mi * 16 + (lane & 15);
          af[mi] = *(const bf16x8*)((const char*)A_ + ar * 128 + ((c16 ^ (ar & 7)) << 4));
        }
        int br = wn * 16 + (lane & 15);
        bf16x8 f1 = *(const bf16x8*)((const char*)B1s[bbuf] + br * 128 + ((c16 ^ (br & 7)) << 4));
        bf16x8 f3 = *(const bf16x8*)((const char*)B3s[bbuf] + br * 128 + ((c16 ^ (br & 7)) << 4));
        __builtin_amdgcn_s_setprio(1);
#pragma unroll
        for (int mi = 0; mi < 4; ++mi) {
          acc1[mi] = __builtin_amdgcn_mfma_f32_16x16x32_bf16(af[mi], f1, acc1[mi], 0, 0, 0);
          acc3[mi] = __builtin_amdgcn_mfma_f32_16x16x32_bf16(af[mi], f3, acc3[mi], 0, 0, 0);
        }
        __builtin_amdgcn_s_setprio(0);
      }
    };

    fvec4 ra1, ra3, rb1, rb3;
    // prologue: A(0); B(0)->ra, B(1)->rb; cvt B(0); B(2)->ra
    STAGE_A(Ab[0], 0);
    LOADB(ra1, ra3, 0);
    LOADB(rb1, rb3, 64);
    asm volatile("s_waitcnt vmcnt(2)" ::: "memory");   // A(0)+B(0) landed
    CVTW(ra1, ra3, 0);
    LOADB(ra1, ra3, 128);
    BARX();

    for (int t = 0; t < NT; ++t) {
      const int cur = t & 1;
      if (t + 1 < NT) STAGE_A(Ab[cur ^ 1], (t + 1) * 64);   // top-of-region issue
      STEP(Ab[cur], cur);
      if (t + 1 < NT) {
        if (cur == 0) { CVTW(rb1, rb3, 1); if (t + 3 < NT) LOADB(rb1, rb3, (t + 3) * 64); }
        else          { CVTW(ra1, ra3, 0); if (t + 3 < NT) LOADB(ra1, ra3, (t + 3) * 64); }
      }
      if (t + 2 < NT) { asm volatile("s_waitcnt vmcnt(2)" ::: "memory"); }
      else            { asm volatile("s_waitcnt vmcnt(0)" ::: "memory"); }
      BARX();
    }

    const int row_lim = (base[e + 1] - ab) - m_base;
#pragma unroll
    for (int mi = 0; mi < 4; ++mi)
#pragma unroll
      for (int j = 0; j < 4; ++j) {
        int row = wm * 64 + mi * 16 + (lane >> 4) * 4 + j;
        if (row < row_lim) {
          float h1 = acc1[mi][j];
          float a = (h1 / (1.f + __expf(-h1))) * acc3[mi][j];
          actb[(size_t)(ab + m_base + row) * I_ + n0 + wn * 16 + (lane & 15)] =
              __builtin_bit_cast(unsigned short, (__bf16)a);
        }
      }
  }
}

// ---- FFN2: persistent, BM=256, BN=32, BK=64, single B ----
__global__ __launch_bounds__(512, 4) void ffn2_kernel(
    const unsigned short* __restrict__ actb, const float* __restrict__ w2,
    const int* __restrict__ cnt, const int* __restrict__ base,
    const int* __restrict__ chunk, const int* __restrict__ tokl,
    const float* __restrict__ gatel, float* __restrict__ out,
    int* __restrict__ wk) {
  const int tid = threadIdx.x;
  const int lane = tid & 63, wv = tid >> 6;
  const int wm = wv >> 1, wn = wv & 1;

  __shared__ unsigned short Ab[2][256 * 64];  // 64 KiB
  __shared__ unsigned short Bs[2][32 * 64];   // 8 KiB  -> 72 KiB
  __shared__ int sItem;

  const int nwork = chunk[0] * 64;            // 64 n-tiles of 32
  const int brow = tid >> 4, w = tid & 15;
  const int wbyte = brow * 128 + (((w >> 1) ^ (brow & 7)) << 4) + (w & 1) * 8;
  const int colg = ((lane & 7) ^ ((lane >> 3) & 7)) * 8;
  const int NT = I_ / 64;                     // 50

  for (;;) {
    __syncthreads();
    if (tid == 0) sItem = atomicAdd(wk, 1);
    __syncthreads();
    const int item = sItem;
    if (item >= nwork) return;
    const int c = item >> 6;
    const int n0 = (item & 63) * 32;
    const int e = chunk[1 + c];
    const int m_base = chunk[1 + MAXCH + c];
    const int ab = base[e];
    const int count = cnt[e];

    const unsigned short* aSrc[4];
#pragma unroll
    for (int i = 0; i < 4; ++i) {
      int r = ab + m_base + wv * 32 + i * 8 + (lane >> 3);
      aSrc[i] = actb + (size_t)r * I_ + colg;
    }
    const float* bp = w2 + ((size_t)e * H_ + n0 + brow) * I_ + w * 4;

    f32x4 acc[4];
#pragma unroll
    for (int mi = 0; mi < 4; ++mi) acc[mi] = (f32x4){0,0,0,0};

    auto STAGE_A = [&](unsigned short* dst, int kb) {
#pragma unroll
      for (int i = 0; i < 4; ++i)
        __builtin_amdgcn_global_load_lds((gp1_t)(aSrc[i] + kb),
                                         (sp3_t)(dst + (wv * 32 + i * 8) * 64), 16, 0, 0);
    };
    auto LOADB = [&](fvec4& r, int kb) { r = *(const fvec4*)(bp + kb); };
    auto CVTW = [&](fvec4& r, int buf) {
      u16x4 v;
#pragma unroll
      for (int cc = 0; cc < 4; ++cc) v[cc] = __builtin_bit_cast(unsigned short, (__bf16)r[cc]);
      *(u16x4*)((char*)Bs[buf] + wbyte) = v;
    };
    auto STEP = [&](const unsigned short* A_, int bbuf) {
#pragma unroll
      for (int kk = 0; kk < 2; ++kk) {
        const int c16 = kk * 4 + (lane >> 4);
        bf16x8 af[4];
#pragma unroll
        for (int mi = 0; mi < 4; ++mi) {
          int ar = wm * 64 + mi * 16 + (lane & 15);
          af[mi] = *(const bf16x8*)((const char*)A_ + ar * 128 + ((c16 ^ (ar & 7)) << 4));
        }
        int br = wn * 16 + (lane & 15);
        bf16x8 f = *(const bf16x8*)((const char*)Bs[bbuf] + br * 128 + ((c16 ^ (br & 7)) << 4));
        __builtin_amdgcn_s_setprio(1);
#pragma unroll
        for (int mi = 0; mi < 4; ++mi)
          acc[mi] = __builtin_amdgcn_mfma_f32_16x16x32_bf16(af[mi], f, acc[mi], 0, 0, 0);
        __builtin_amdgcn_s_setprio(0);
      }
    };

    fvec4 ra, rb;
    STAGE_A(Ab[0], 0);
    LOADB(ra, 0);
    LOADB(rb, 64);
    asm volatile("s_waitcnt vmcnt(1)" ::: "memory");
    CVTW(ra, 0);
    LOADB(ra, 128);
    BARX();

    for (int t = 0; t < NT; ++t) {
      const int cur = t & 1;
      if (t + 1 < NT) STAGE_A(Ab[cur ^ 1], (t + 1) * 64);
      STEP(Ab[cur], cur);
      if (t + 1 < NT) {
        if (cur == 0) { CVTW(rb, 1); if (t + 3 < NT) LOADB(rb, (t + 3) * 64); }
        else          { CVTW(ra, 0); if (t + 3 < NT) LOADB(ra, (t + 3) * 64); }
      }
      if (t + 2 < NT) { asm volatile("s_waitcnt vmcnt(1)" ::: "memory"); }
      else            { asm volatile("s_waitcnt vmcnt(0)" ::: "memory"); }
      BARX();
    }

#pragma unroll
    for (int mi = 0; mi < 4; ++mi)
#pragma unroll
      for (int j = 0; j < 4; ++j) {
        int row = m_base + wm * 64 + mi * 16 + (lane >> 4) * 4 + j;
        if (row < count) {
          int tokv = tokl[e * T_ + row];
          float g = gatel[e * T_ + row];
          atomicAdd(&out[(size_t)tokv * H_ + n0 + wn * 16 + (lane & 15)], g * acc[mi][j]);
        }
      }
  }
}

extern "C" void kernel_launch(void* const* d_in, const int* in_sizes, int n_in,
                              void* d_out, int out_size, void* d_ws, size_t ws_size,
                              hipStream_t stream) {
  const float* x  = (const float*)d_in[0];
  const float* gw = (const float*)d_in[1];
  const float* w1 = (const float*)d_in[2];
  const float* w3 = (const float*)d_in[3];
  const float* w2 = (const float*)d_in[4];
  float* out = (float*)d_out;
  char* ws = (char*)d_ws;

  int* cnt = (int*)ws;
  int* wk1 = (int*)(ws + 32);
  int* wk2 = (int*)(ws + 36);
  int* base = (int*)(ws + 64);
  int* chunk = (int*)(ws + WS_CHUNK);
  int* tokl = (int*)(ws + WS_TOK);
  float* gatel = (float*)(ws + WS_GATE);
  unsigned short* xb = (unsigned short*)(ws + WS_XB);
  unsigned short* actb = (unsigned short*)(ws + WS_ACT);

  (void)hipMemsetAsync(d_out, 0, (size_t)T_ * H_ * sizeof(float), stream);
  (void)hipMemsetAsync(ws, 0, 64, stream);

  router_kernel<<<T_ / 4, 256, 0, stream>>>(x, gw, cnt, tokl, gatel, xb);
  prefix_kernel<<<1, 64, 0, stream>>>(cnt, base, chunk);
  ffn1_kernel<<<512, 512, 0, stream>>>(xb, w1, w3, cnt, base, chunk, tokl, actb, wk1);
  ffn2_kernel<<<512, 512, 0, stream>>>(actb, w2, cnt, base, chunk, tokl, gatel, out, wk2);
}

// Round 9
// 311.433 us; speedup vs baseline: 1.4328x; 1.4328x over previous
//
#include <hip/hip_runtime.h>

#define T_ 1024
#define H_ 2048
#define I_ 3200
#define E_ 8

typedef float fvec4 __attribute__((ext_vector_type(4)));
typedef float f32x4 __attribute__((ext_vector_type(4)));
typedef __bf16 bf16x8 __attribute__((ext_vector_type(8)));
typedef unsigned short u16x4 __attribute__((ext_vector_type(4)));

typedef const __attribute__((address_space(1))) void* gp1_t;
typedef __attribute__((address_space(3))) void* sp3_t;

// ---- ws layout (bytes) ----
#define WS_CHUNK 128
#define WS_TOK   512
#define WS_GATE  33280
#define WS_XB    66560
#define WS_ACT   4261888   // 3328 rows x 3200 bf16 (slack rows OOB-safe)
#define MAXCH    20

#define BARX() { asm volatile("s_waitcnt lgkmcnt(0)" ::: "memory"); \
    __builtin_amdgcn_sched_barrier(0); __builtin_amdgcn_s_barrier(); \
    __builtin_amdgcn_sched_barrier(0); }

// ---------------- router + sparsemixer + list build + x->bf16 ----------------
__global__ __launch_bounds__(256) void router_kernel(const float* __restrict__ x,
                                                     const float* __restrict__ gw,
                                                     int* __restrict__ cnt,
                                                     int* __restrict__ tok,
                                                     float* __restrict__ gate,
                                                     unsigned short* __restrict__ xb) {
  const int lane = threadIdx.x & 63;
  const int wv = threadIdx.x >> 6;
  const int t = blockIdx.x * 4 + wv;

  const float* xp = x + (size_t)t * H_;
  fvec4 xr[8];
#pragma unroll
  for (int j = 0; j < 8; ++j) xr[j] = *(const fvec4*)(xp + j * 256 + lane * 4);

  unsigned short* xbp = xb + (size_t)t * H_;
#pragma unroll
  for (int j = 0; j < 8; ++j) {
    u16x4 o;
#pragma unroll
    for (int c = 0; c < 4; ++c) o[c] = __builtin_bit_cast(unsigned short, (__bf16)xr[j][c]);
    *(u16x4*)(xbp + j * 256 + lane * 4) = o;
  }

  float s[E_];
#pragma unroll
  for (int e = 0; e < E_; ++e) {
    const float* gp = gw + (size_t)e * H_;
    float p = 0.f;
#pragma unroll
    for (int j = 0; j < 8; ++j) {
      fvec4 g = *(const fvec4*)(gp + j * 256 + lane * 4);
      p = fmaf(xr[j][0], g[0], p); p = fmaf(xr[j][1], g[1], p);
      p = fmaf(xr[j][2], g[2], p); p = fmaf(xr[j][3], g[3], p);
    }
#pragma unroll
    for (int off = 32; off > 0; off >>= 1) p += __shfl_xor(p, off);
    s[e] = p;
  }

  float max1 = s[0]; int i1 = 0;
#pragma unroll
  for (int e = 1; e < E_; ++e) if (s[e] > max1) { max1 = s[e]; i1 = e; }
  float den1 = 0.f;
#pragma unroll
  for (int e = 0; e < E_; ++e) {
    float factor = fmaxf(fabsf(s[e]), max1);
    if ((max1 - s[e]) <= 0.02f * factor) den1 += expf(s[e] - max1);
  }
  float mult1 = 1.f / den1;

  float max2 = -INFINITY; int i2 = 0;
#pragma unroll
  for (int e = 0; e < E_; ++e) if (e != i1 && s[e] > max2) { max2 = s[e]; i2 = e; }
  float den2 = 0.f;
#pragma unroll
  for (int e = 0; e < E_; ++e) {
    if (e == i1) continue;
    float factor = fmaxf(fabsf(s[e]), max2);
    if ((max2 - s[e]) <= 0.02f * factor) den2 += expf(s[e] - max2);
  }
  float mult2 = 1.f / den2;

  if (lane == 0) {
    int p1 = atomicAdd(&cnt[i1], 1); tok[i1 * T_ + p1] = t; gate[i1 * T_ + p1] = mult1;
    int p2 = atomicAdd(&cnt[i2], 1); tok[i2 * T_ + p2] = t; gate[i2 * T_ + p2] = mult2;
  }
}

// ---------------- prefix (128-pad) + chunk table (256-row chunks) ----------------
__global__ void prefix_kernel(const int* __restrict__ cnt, int* __restrict__ base,
                              int* __restrict__ chunk) {
  if (threadIdx.x == 0 && blockIdx.x == 0) {
    int a = 0, c = 0;
    for (int e = 0; e < E_; ++e) {
      base[e] = a;
      int pc = (cnt[e] + 127) & ~127;
      for (int m = 0; m < pc; m += 256) { chunk[1 + c] = e; chunk[1 + MAXCH + c] = m; ++c; }
      a += pc;
    }
    base[E_] = a;
    chunk[0] = c;
  }
}

// ---- FFN1: BM=256, BN=32, BK=64, 8 waves, 1 barrier/region, B 3-deep regs ----
__global__ __launch_bounds__(512, 4) void ffn1_kernel(
    const unsigned short* __restrict__ xb, const float* __restrict__ w1,
    const float* __restrict__ w3, const int* __restrict__ cnt,
    const int* __restrict__ base, const int* __restrict__ chunk,
    const int* __restrict__ tokl, unsigned short* __restrict__ actb) {
  if ((int)blockIdx.y >= chunk[0]) return;
  const int e = chunk[1 + blockIdx.y];
  const int m_base = chunk[1 + MAXCH + blockIdx.y];
  const int ab = base[e];
  const int count = cnt[e];
  const int n0 = blockIdx.x * 32;
  const int tid = threadIdx.x;
  const int lane = tid & 63, wv = tid >> 6;   // 8 waves
  const int wm = wv >> 1, wn = wv & 1;        // per-wave 64x16 out

  __shared__ unsigned short Ab[2][256 * 64];  // 64 KiB
  __shared__ unsigned short B1s[2][32 * 64];  // 8 KiB
  __shared__ unsigned short B3s[2][32 * 64];  // 8 KiB   -> exactly 80 KiB

  const unsigned short* aSrc[4];
  const int colg = ((lane & 7) ^ ((lane >> 3) & 7)) * 8;
#pragma unroll
  for (int i = 0; i < 4; ++i) {
    int r = m_base + wv * 32 + i * 8 + (lane >> 3);
    if (r >= count) r = count - 1;
    aSrc[i] = xb + (size_t)tokl[e * T_ + r] * H_ + colg;
  }
  const int brow = tid >> 4, w = tid & 15;
  const float* b1p = w1 + ((size_t)e * I_ + n0 + brow) * H_ + w * 4;
  const float* b3p = w3 + ((size_t)e * I_ + n0 + brow) * H_ + w * 4;
  const int wbyte = brow * 128 + (((w >> 1) ^ (brow & 7)) << 4) + (w & 1) * 8;

  f32x4 acc1[4], acc3[4];
#pragma unroll
  for (int mi = 0; mi < 4; ++mi) { acc1[mi] = (f32x4){0,0,0,0}; acc3[mi] = (f32x4){0,0,0,0}; }

  auto STAGE_A = [&](unsigned short* dst, int kb) {
#pragma unroll
    for (int i = 0; i < 4; ++i)
      __builtin_amdgcn_global_load_lds((gp1_t)(aSrc[i] + kb),
                                       (sp3_t)(dst + (wv * 32 + i * 8) * 64), 16, 0, 0);
  };
  auto CVTW = [&](fvec4& r1, fvec4& r3, int buf) {
    u16x4 v, u;
#pragma unroll
    for (int cc = 0; cc < 4; ++cc) {
      v[cc] = __builtin_bit_cast(unsigned short, (__bf16)r1[cc]);
      u[cc] = __builtin_bit_cast(unsigned short, (__bf16)r3[cc]);
    }
    *(u16x4*)((char*)B1s[buf] + wbyte) = v;
    *(u16x4*)((char*)B3s[buf] + wbyte) = u;
  };
  auto STEP = [&](const unsigned short* A_, int bbuf) {
#pragma unroll
    for (int kk = 0; kk < 2; ++kk) {
      const int c16 = kk * 4 + (lane >> 4);
      bf16x8 af[4];
#pragma unroll
      for (int mi = 0; mi < 4; ++mi) {
        int ar = wm * 64 + mi * 16 + (lane & 15);
        af[mi] = *(const bf16x8*)((const char*)A_ + ar * 128 + ((c16 ^ (ar & 7)) << 4));
      }
      int br = wn * 16 + (lane & 15);
      bf16x8 f1 = *(const bf16x8*)((const char*)B1s[bbuf] + br * 128 + ((c16 ^ (br & 7)) << 4));
      bf16x8 f3 = *(const bf16x8*)((const char*)B3s[bbuf] + br * 128 + ((c16 ^ (br & 7)) << 4));
      __builtin_amdgcn_s_setprio(1);
#pragma unroll
      for (int mi = 0; mi < 4; ++mi) {
        acc1[mi] = __builtin_amdgcn_mfma_f32_16x16x32_bf16(af[mi], f1, acc1[mi], 0, 0, 0);
        acc3[mi] = __builtin_amdgcn_mfma_f32_16x16x32_bf16(af[mi], f3, acc3[mi], 0, 0, 0);
      }
      __builtin_amdgcn_s_setprio(0);
    }
  };

  const int NT = H_ / 64;  // 32
  // B register sets (named rotation, no dynamic indexing)
  fvec4 cv1, cv3;   // B(t+1): landed, convert this region
  fvec4 fl1, fl3;   // B(t+2): in flight
  fvec4 fr1, fr3;   // free -> loads B(t+3)

  // prologue
  STAGE_A(Ab[0], 0);                                     // 4 glds
  fr1 = *(const fvec4*)(b1p);       fr3 = *(const fvec4*)(b3p);        // B0
  cv1 = *(const fvec4*)(b1p + 64);  cv3 = *(const fvec4*)(b3p + 64);   // B1
  fl1 = *(const fvec4*)(b1p + 128); fl3 = *(const fvec4*)(b3p + 128);  // B2
  asm volatile("s_waitcnt vmcnt(2)" ::: "memory");       // A0,B0,B1 landed; B2 flies
  CVTW(fr1, fr3, 0);                                     // B0 -> buf0; fr set now free
  BARX();

  for (int t = 0; t < NT; ++t) {
    const int cur = t & 1;
    if (t + 1 < NT) {
      STAGE_A(Ab[cur ^ 1], (t + 1) * 64);                // A(t+1), WAR-safe
      CVTW(cv1, cv3, cur ^ 1);                           // B(t+1) -> other buf
    }
    if (t + 3 < NT) {
      fr1 = *(const fvec4*)(b1p + (t + 3) * 64);         // B(t+3)
      fr3 = *(const fvec4*)(b3p + (t + 3) * 64);
    }
    STEP(Ab[cur], cur);
    if (t + 3 < NT) { asm volatile("s_waitcnt vmcnt(2)" ::: "memory"); }
    else            { asm volatile("s_waitcnt vmcnt(0)" ::: "memory"); }
    BARX();
    // rotate: cv <- fl, fl <- fr, fr <- old cv (free)
    fvec4 z1 = cv1, z3 = cv3;
    cv1 = fl1; cv3 = fl3;
    fl1 = fr1; fl3 = fr3;
    fr1 = z1;  fr3 = z3;
  }

  const int row_lim = (base[e + 1] - ab) - m_base;
#pragma unroll
  for (int mi = 0; mi < 4; ++mi)
#pragma unroll
    for (int j = 0; j < 4; ++j) {
      int row = wm * 64 + mi * 16 + (lane >> 4) * 4 + j;
      if (row < row_lim) {
        float h1 = acc1[mi][j];
        float a = (h1 / (1.f + __expf(-h1))) * acc3[mi][j];
        actb[(size_t)(ab + m_base + row) * I_ + n0 + wn * 16 + (lane & 15)] =
            __builtin_bit_cast(unsigned short, (__bf16)a);
      }
    }
}

// ---- FFN2: BM=256, BN=64, BK=64, 8 waves (2m x 4n), single B, same pipeline ----
__global__ __launch_bounds__(512, 4) void ffn2_kernel(
    const unsigned short* __restrict__ actb, const float* __restrict__ w2,
    const int* __restrict__ cnt, const int* __restrict__ base,
    const int* __restrict__ chunk, const int* __restrict__ tokl,
    const float* __restrict__ gatel, float* __restrict__ out) {
  if ((int)blockIdx.y >= chunk[0]) return;
  const int e = chunk[1 + blockIdx.y];
  const int m_base = chunk[1 + MAXCH + blockIdx.y];
  const int count = cnt[e];
  if (m_base >= count) return;
  const int ab = base[e];
  const int n0 = blockIdx.x * 64;
  const int tid = threadIdx.x;
  const int lane = tid & 63, wv = tid >> 6;
  const int wm = wv >> 2, wn = wv & 3;        // 2m x 4n; per-wave 128x16 out

  __shared__ unsigned short Ab[2][256 * 64];  // 64 KiB
  __shared__ unsigned short Bs[2][64 * 64];   // 16 KiB -> exactly 80 KiB

  const unsigned short* aSrc[4];
  const int colg = ((lane & 7) ^ ((lane >> 3) & 7)) * 8;
#pragma unroll
  for (int i = 0; i < 4; ++i) {
    int r = ab + m_base + wv * 32 + i * 8 + (lane >> 3);
    aSrc[i] = actb + (size_t)r * I_ + colg;
  }
  const int brow = tid >> 3, w = tid & 7;     // 64 rows, 8 f32/lane
  const float* bp = w2 + ((size_t)e * H_ + n0 + brow) * I_ + w * 8;
  const int wbyte = brow * 128 + ((w ^ (brow & 7)) << 4);

  f32x4 acc[8];
#pragma unroll
  for (int mi = 0; mi < 8; ++mi) acc[mi] = (f32x4){0,0,0,0};

  auto STAGE_A = [&](unsigned short* dst, int kb) {
#pragma unroll
    for (int i = 0; i < 4; ++i)
      __builtin_amdgcn_global_load_lds((gp1_t)(aSrc[i] + kb),
                                       (sp3_t)(dst + (wv * 32 + i * 8) * 64), 16, 0, 0);
  };
  auto CVTW = [&](fvec4& r0, fvec4& r1, int buf) {
    bf16x8 v;
#pragma unroll
    for (int cc = 0; cc < 4; ++cc) { v[cc] = (__bf16)r0[cc]; v[cc + 4] = (__bf16)r1[cc]; }
    *(bf16x8*)((char*)Bs[buf] + wbyte) = v;
  };
  auto STEP = [&](const unsigned short* A_, int bbuf) {
#pragma unroll
    for (int kk = 0; kk < 2; ++kk) {
      const int c16 = kk * 4 + (lane >> 4);
      int br = wn * 16 + (lane & 15);
      bf16x8 f = *(const bf16x8*)((const char*)Bs[bbuf] + br * 128 + ((c16 ^ (br & 7)) << 4));
      __builtin_amdgcn_s_setprio(1);
#pragma unroll
      for (int mi = 0; mi < 8; ++mi) {
        int ar = wm * 128 + mi * 16 + (lane & 15);
        bf16x8 af = *(const bf16x8*)((const char*)A_ + ar * 128 + ((c16 ^ (ar & 7)) << 4));
        acc[mi] = __builtin_amdgcn_mfma_f32_16x16x32_bf16(af, f, acc[mi], 0, 0, 0);
      }
      __builtin_amdgcn_s_setprio(0);
    }
  };

  const int NT = I_ / 64;  // 50
  fvec4 cv0, cv1, fl0, fl1, fr0, fr1;

  STAGE_A(Ab[0], 0);
  fr0 = *(const fvec4*)(bp);       fr1 = *(const fvec4*)(bp + 4);       // B0
  cv0 = *(const fvec4*)(bp + 64);  cv1 = *(const fvec4*)(bp + 68);      // B1
  fl0 = *(const fvec4*)(bp + 128); fl1 = *(const fvec4*)(bp + 132);     // B2
  asm volatile("s_waitcnt vmcnt(2)" ::: "memory");
  CVTW(fr0, fr1, 0);
  BARX();

  for (int t = 0; t < NT; ++t) {
    const int cur = t & 1;
    if (t + 1 < NT) {
      STAGE_A(Ab[cur ^ 1], (t + 1) * 64);
      CVTW(cv0, cv1, cur ^ 1);
    }
    if (t + 3 < NT) {
      fr0 = *(const fvec4*)(bp + (t + 3) * 64);
      fr1 = *(const fvec4*)(bp + (t + 3) * 64 + 4);
    }
    STEP(Ab[cur], cur);
    if (t + 3 < NT) { asm volatile("s_waitcnt vmcnt(2)" ::: "memory"); }
    else            { asm volatile("s_waitcnt vmcnt(0)" ::: "memory"); }
    BARX();
    fvec4 z0 = cv0, z1 = cv1;
    cv0 = fl0; cv1 = fl1;
    fl0 = fr0; fl1 = fr1;
    fr0 = z0;  fr1 = z1;
  }

#pragma unroll
  for (int mi = 0; mi < 8; ++mi)
#pragma unroll
    for (int j = 0; j < 4; ++j) {
      int row = m_base + wm * 128 + mi * 16 + (lane >> 4) * 4 + j;
      if (row < count) {
        int tokv = tokl[e * T_ + row];
        float g = gatel[e * T_ + row];
        atomicAdd(&out[(size_t)tokv * H_ + n0 + wn * 16 + (lane & 15)], g * acc[mi][j]);
      }
    }
}

extern "C" void kernel_launch(void* const* d_in, const int* in_sizes, int n_in,
                              void* d_out, int out_size, void* d_ws, size_t ws_size,
                              hipStream_t stream) {
  const float* x  = (const float*)d_in[0];
  const float* gw = (const float*)d_in[1];
  const float* w1 = (const float*)d_in[2];
  const float* w3 = (const float*)d_in[3];
  const float* w2 = (const float*)d_in[4];
  float* out = (float*)d_out;
  char* ws = (char*)d_ws;

  int* cnt = (int*)ws;
  int* base = (int*)(ws + 64);
  int* chunk = (int*)(ws + WS_CHUNK);
  int* tokl = (int*)(ws + WS_TOK);
  float* gatel = (float*)(ws + WS_GATE);
  unsigned short* xb = (unsigned short*)(ws + WS_XB);
  unsigned short* actb = (unsigned short*)(ws + WS_ACT);

  (void)hipMemsetAsync(d_out, 0, (size_t)T_ * H_ * sizeof(float), stream);
  (void)hipMemsetAsync(ws, 0, 64, stream);

  router_kernel<<<T_ / 4, 256, 0, stream>>>(x, gw, cnt, tokl, gatel, xb);
  prefix_kernel<<<1, 64, 0, stream>>>(cnt, base, chunk);
  ffn1_kernel<<<dim3(I_ / 32, MAXCH), 512, 0, stream>>>(xb, w1, w3, cnt, base, chunk, tokl, actb);
  ffn2_kernel<<<dim3(H_ / 64, MAXCH), 512, 0, stream>>>(actb, w2, cnt, base, chunk, tokl, gatel, out);
}